// Round 8
// baseline (42.719 us; speedup 1.0000x reference)
//
#include <hip/hip_runtime.h>
#include <math.h>

#define NFEAT 32
#define EMB   30
#define ATT   10
#define NPAIR 496   // 32*31/2
#define BLK   128
#define WPB   2     // waves per block = batch elements per block
#define ROWSTR 36   // padded x-row stride in floats (144B; 4-bank shift per row)

typedef float v2f __attribute__((ext_vector_type(2)));

// Forced VOP3P: acc += broadcast(pr.lo or pr.hi) * w   (w in SGPR pair)
#define PK_FMA_BCLO(acc, pr, w) \
    asm("v_pk_fma_f32 %0, %1, %2, %0 op_sel:[0,0,0] op_sel_hi:[0,1,1]" \
        : "+v"(acc) : "v"(pr), "s"(w))
#define PK_FMA_BCHI(acc, pr, w) \
    asm("v_pk_fma_f32 %0, %1, %2, %0 op_sel:[1,0,0] op_sel_hi:[1,1,1]" \
        : "+v"(acc) : "v"(pr), "s"(w))
#define PK_FMA(acc, a, b) \
    asm("v_pk_fma_f32 %0, %1, %2, %0" : "+v"(acc) : "v"(a), "s"(b))
#define PK_MUL(d, a, b) \
    asm("v_pk_mul_f32 %0, %1, %2" : "=v"(d) : "v"(a), "v"(b))

// R7 WIN (53.5->37.7us): 2x2 tiles halved LDS reads -> LDS stream was binding.
// Now latency-exposed: 4 dependent ds_read_b128 per eg, ~16 stall points/chunk,
// per-SIMD VALU duty only ~22%. R8: explicit eg-prefetch pipeline -- convert
// current reads to pr[], issue next eg's 4 reads, THEN the 96-pk FMA block
// (192cy window > 120cy LDS latency -> in-wave latency hiding).
__global__ __launch_bounds__(BLK) __attribute__((amdgpu_waves_per_eu(3)))
void attn_net_kernel(const float* __restrict__ x,
                     const float* __restrict__ W,
                     const float* __restrict__ bias,
                     const float* __restrict__ h,
                     const float* __restrict__ pvec,
                     float* __restrict__ out)
{
    __shared__ __align__(16) float sx[WPB * NFEAT * ROWSTR];  // 9 KiB

    const int t    = threadIdx.x;
    const int wid  = t >> 6;
    const int lane = t & 63;
    const int b    = blockIdx.x * WPB + wid;

    // ---- stage x[b] into this wave's padded LDS rows (wave-private: no barrier).
    //      cols 30..35 uninitialized: eg=7 consumes only e=28,29. ----
    float* swx = sx + wid * (NFEAT * ROWSTR);
    {
        const float4* xin = reinterpret_cast<const float4*>(x + (size_t)b * (NFEAT * EMB));
        for (int v = lane; v < 240; v += 64) {          // exactly 240 float4s
            const float4 d = xin[v];
            const int ef = 4 * v;
            #pragma unroll
            for (int u = 0; u < 4; ++u) {
                const int e = ef + u;
                const int r = e / EMB;
                const int c = e - r * EMB;
                swx[r * ROWSTR + c] = ((const float*)&d)[u];
            }
        }
    }

    // ---- uniform params (scalar s_loads -> SGPRs) ----
    v2f b2[5], h2[5];
    #pragma unroll
    for (int a2 = 0; a2 < 5; ++a2) {
        b2[a2] = v2f{bias[2 * a2], bias[2 * a2 + 1]};
        h2[a2] = v2f{h[2 * a2],    h[2 * a2 + 1]};
    }

    // ---- per-lane: 2 chunks x one 2x2 tile (4 pairs); online softmax ----
    float m = -INFINITY, se = 0.f, sec = 0.f;

    #pragma unroll
    for (int ch = 0; ch < 2; ++ch) {
        const int T = ch * 64 + lane;
        const bool special = (T >= 120);                // only ch==1, lanes 56..63
        int r0, r1, c0, c1;
        if (special) {
            const int s7 = T - 120;
            r0 = 4 * s7; r1 = r0 + 2; c0 = r0 + 1; c1 = r0 + 3;
        } else {
            // n=16 triu inversion; exact: 961-8*T_I=(31-2I)^2, margin>=4/29
            const float sq = sqrtf((float)(961 - 8 * T));
            const int I = (int)((31.0f - sq) * 0.5f);
            const int J = I + 1 + (T - ((I * (31 - I)) >> 1));
            r0 = 2 * I; r1 = r0 + 1; c0 = 2 * J; c1 = c0 + 1;
        }
        const int oi0 = r0 * ROWSTR, oi1 = r1 * ROWSTR;
        const int oj0 = c0 * ROWSTR, oj1 = c1 * ROWSTR;

        // slots: 0:(r0,c0) 1:(r0,c1) 2:(r1,c0) 3:(r1,c1); special masks 1,2
        v2f acc[4][5];                                  // 40 VGPR
        v2f accC[4];                                    // 8 VGPR (e-pair packed)
        #pragma unroll
        for (int p = 0; p < 4; ++p) {
            #pragma unroll
            for (int a2 = 0; a2 < 5; ++a2) acc[p][a2] = b2[a2];
            accC[p] = v2f{0.f, 0.f};
        }

        // ---- prologue: prefetch eg=0's four row slices ----
        float4 pxi0 = *reinterpret_cast<const float4*>(&swx[oi0]);
        float4 pxi1 = *reinterpret_cast<const float4*>(&swx[oi1]);
        float4 pxj0 = *reinterpret_cast<const float4*>(&swx[oj0]);
        float4 pxj1 = *reinterpret_cast<const float4*>(&swx[oj1]);

        #pragma unroll
        for (int eg = 0; eg < 8; ++eg) {                // e-groups of 4; eg=7 -> e=28,29
            const int e0 = eg * 4;
            const bool full = (eg < 7);

            // (1) consume prefetched slices into products (frees the regs)
            v2f prL[4], prH[4];
            {
                const v2f* i0 = reinterpret_cast<const v2f*>(&pxi0);
                const v2f* i1 = reinterpret_cast<const v2f*>(&pxi1);
                const v2f* j0 = reinterpret_cast<const v2f*>(&pxj0);
                const v2f* j1 = reinterpret_cast<const v2f*>(&pxj1);
                PK_MUL(prL[0], i0[0], j0[0]);
                PK_MUL(prL[1], i0[0], j1[0]);
                PK_MUL(prL[2], i1[0], j0[0]);
                PK_MUL(prL[3], i1[0], j1[0]);
                if (full) {
                    PK_MUL(prH[0], i0[1], j0[1]);
                    PK_MUL(prH[1], i0[1], j1[1]);
                    PK_MUL(prH[2], i1[1], j0[1]);
                    PK_MUL(prH[3], i1[1], j1[1]);
                }
            }

            // (2) issue next eg's reads NOW (latency hides under the FMA block)
            if (eg < 7) {
                pxi0 = *reinterpret_cast<const float4*>(&swx[oi0 + e0 + 4]);
                pxi1 = *reinterpret_cast<const float4*>(&swx[oi1 + e0 + 4]);
                pxj0 = *reinterpret_cast<const float4*>(&swx[oj0 + e0 + 4]);
                pxj1 = *reinterpret_cast<const float4*>(&swx[oj1 + e0 + 4]);
            }

            // (3) W rows for this e-group -> SGPR pairs (shared by all 4 pairs)
            v2f wa[5], wb[5], wc[5], wd[5];
            #pragma unroll
            for (int a2 = 0; a2 < 5; ++a2) {
                wa[a2] = v2f{W[(e0    ) * ATT + 2*a2], W[(e0    ) * ATT + 2*a2 + 1]};
                wb[a2] = v2f{W[(e0 + 1) * ATT + 2*a2], W[(e0 + 1) * ATT + 2*a2 + 1]};
            }
            if (full) {
                #pragma unroll
                for (int a2 = 0; a2 < 5; ++a2) {
                    wc[a2] = v2f{W[(e0 + 2) * ATT + 2*a2], W[(e0 + 2) * ATT + 2*a2 + 1]};
                    wd[a2] = v2f{W[(e0 + 3) * ATT + 2*a2], W[(e0 + 3) * ATT + 2*a2 + 1]};
                }
            }
            const v2f pv01 = v2f{pvec[e0], pvec[e0 + 1]};
            v2f pv23 = v2f{0.f, 0.f};
            if (full) pv23 = v2f{pvec[e0 + 2], pvec[e0 + 3]};

            // (4) FMA block: 4 pairs x (10 or 20) pk-fma + pvec accum
            #pragma unroll
            for (int p = 0; p < 4; ++p) {
                #pragma unroll
                for (int a2 = 0; a2 < 5; ++a2) PK_FMA_BCLO(acc[p][a2], prL[p], wa[a2]);
                #pragma unroll
                for (int a2 = 0; a2 < 5; ++a2) PK_FMA_BCHI(acc[p][a2], prL[p], wb[a2]);
                PK_FMA(accC[p], prL[p], pv01);
                if (full) {
                    #pragma unroll
                    for (int a2 = 0; a2 < 5; ++a2) PK_FMA_BCLO(acc[p][a2], prH[p], wc[a2]);
                    #pragma unroll
                    for (int a2 = 0; a2 < 5; ++a2) PK_FMA_BCHI(acc[p][a2], prH[p], wd[a2]);
                    PK_FMA(accC[p], prH[p], pv23);
                }
            }
        }

        float s4[4], cv4[4];
        #pragma unroll
        for (int p = 0; p < 4; ++p) {
            const v2f z = v2f{0.f, 0.f};
            v2f sv = z;
            #pragma unroll
            for (int a2 = 0; a2 < 5; ++a2) {
                const v2f r = __builtin_elementwise_max(acc[p][a2], z);
                sv = __builtin_elementwise_fma(r, h2[a2], sv);
            }
            s4[p]  = sv.x + sv.y;
            cv4[p] = accC[p].x + accC[p].y;
        }
        if (special) { s4[1] = -INFINITY; s4[2] = -INFINITY; }  // dup / i>j slots

        // online merge (ch=0: m=-inf -> scale=0, clean start)
        const float nm = fmaxf(m, fmaxf(fmaxf(s4[0], s4[1]), fmaxf(s4[2], s4[3])));
        const float scale = __expf(m - nm);
        se  *= scale;
        sec *= scale;
        #pragma unroll
        for (int p = 0; p < 4; ++p) {
            const float E = __expf(s4[p] - nm);         // exp(-inf)=0 for masked
            se += E;
            sec = fmaf(E, cv4[p], sec);
        }
        m = nm;
    }

    // ---- tail: global max first, one rescale, then add-butterflies ----
    float M = m;
    #pragma unroll
    for (int o = 1; o < 64; o <<= 1) M = fmaxf(M, __shfl_xor(M, o, 64));
    const float rs = __expf(m - M);
    se  *= rs;
    sec *= rs;
    #pragma unroll
    for (int o = 1; o < 64; o <<= 1) {
        se  += __shfl_xor(se,  o, 64);
        sec += __shfl_xor(sec, o, 64);
    }
    if (lane == 0) out[b] = sec / se;
}

extern "C" void kernel_launch(void* const* d_in, const int* in_sizes, int n_in,
                              void* d_out, int out_size, void* d_ws, size_t ws_size,
                              hipStream_t stream) {
    const float* x    = (const float*)d_in[0];
    const float* W    = (const float*)d_in[1];
    const float* bias = (const float*)d_in[2];
    const float* h    = (const float*)d_in[3];
    const float* pvec = (const float*)d_in[4];
    float* out = (float*)d_out;

    const int B = in_sizes[0] / (NFEAT * EMB);   // 8192
    attn_net_kernel<<<B / WPB, BLK, 0, stream>>>(x, W, bias, h, pvec, out);
}

// Round 9
// 41.000 us; speedup vs baseline: 1.0419x; 1.0419x over previous
//
#include <hip/hip_runtime.h>
#include <math.h>

#define NFEAT 32
#define EMB   30
#define ATT   10
#define NPAIR 496   // 32*31/2
#define BLK   128   // 2 waves, BOTH on the same batch
#define ROWSTR 36   // padded x-row stride in floats (144B; 4-bank shift per row)

typedef float v2f __attribute__((ext_vector_type(2)));

// Forced VOP3P: acc += broadcast(pr.lo or pr.hi) * w   (w in SGPR pair)
#define PK_FMA_BCLO(acc, pr, w) \
    asm("v_pk_fma_f32 %0, %1, %2, %0 op_sel:[0,0,0] op_sel_hi:[0,1,1]" \
        : "+v"(acc) : "v"(pr), "s"(w))
#define PK_FMA_BCHI(acc, pr, w) \
    asm("v_pk_fma_f32 %0, %1, %2, %0 op_sel:[1,0,0] op_sel_hi:[1,1,1]" \
        : "+v"(acc) : "v"(pr), "s"(w))
#define PK_FMA(acc, a, b) \
    asm("v_pk_fma_f32 %0, %1, %2, %0" : "+v"(acc) : "v"(a), "s"(b))
#define PK_MUL(d, a, b) \
    asm("v_pk_mul_f32 %0, %1, %2" : "=v"(d) : "v"(a), "v"(b))

// R8 FAILED (manual prefetch: +12 VGPR, worse schedule) -> reverted to R7's
// read-at-use inner loop. R9: 1 batch/block, 1 chunk/wave -- per-wave serial
// chain halves, 8192 fine-grain blocks keep CUs topped up (R7 occupancy 31%),
// online-softmax rescale deleted (single chunk), staging cooperative.
__global__ __launch_bounds__(BLK) __attribute__((amdgpu_waves_per_eu(3)))
void attn_net_kernel(const float* __restrict__ x,
                     const float* __restrict__ W,
                     const float* __restrict__ bias,
                     const float* __restrict__ h,
                     const float* __restrict__ pvec,
                     float* __restrict__ out)
{
    __shared__ __align__(16) float sx[NFEAT * ROWSTR];   // 4.5 KiB, one batch
    __shared__ float red[2][3];                           // per-wave (m,se,sec)

    const int t    = threadIdx.x;
    const int wid  = t >> 6;
    const int lane = t & 63;
    const int b    = blockIdx.x;

    // ---- cooperative stage of x[b] (both waves), padded rows ----
    {
        const float4* xin = reinterpret_cast<const float4*>(x + (size_t)b * (NFEAT * EMB));
        for (int v = t; v < 240; v += BLK) {             // exactly 240 float4s
            const float4 d = xin[v];
            const int ef = 4 * v;
            #pragma unroll
            for (int u = 0; u < 4; ++u) {
                const int e = ef + u;
                const int r = e / EMB;
                const int c = e - r * EMB;
                sx[r * ROWSTR + c] = ((const float*)&d)[u];
            }
        }
    }

    // ---- uniform params (scalar s_loads -> SGPRs) ----
    v2f b2[5], h2[5];
    #pragma unroll
    for (int a2 = 0; a2 < 5; ++a2) {
        b2[a2] = v2f{bias[2 * a2], bias[2 * a2 + 1]};
        h2[a2] = v2f{h[2 * a2],    h[2 * a2 + 1]};
    }

    __syncthreads();                                     // sx ready for both waves

    // ---- this wave's 64 tiles: T = wid*64 + lane ----
    const int T = wid * 64 + lane;
    const bool special = (T >= 120);                     // wave 1, lanes 56..63
    int r0, r1, c0, c1;
    if (special) {
        const int s7 = T - 120;
        r0 = 4 * s7; r1 = r0 + 2; c0 = r0 + 1; c1 = r0 + 3;
    } else {
        // n=16 triu inversion; exact: 961-8*T_I=(31-2I)^2, margin>=4/29
        const float sq = sqrtf((float)(961 - 8 * T));
        const int I = (int)((31.0f - sq) * 0.5f);
        const int J = I + 1 + (T - ((I * (31 - I)) >> 1));
        r0 = 2 * I; r1 = r0 + 1; c0 = 2 * J; c1 = c0 + 1;
    }
    const int oi0 = r0 * ROWSTR, oi1 = r1 * ROWSTR;
    const int oj0 = c0 * ROWSTR, oj1 = c1 * ROWSTR;

    // slots: 0:(r0,c0) 1:(r0,c1) 2:(r1,c0) 3:(r1,c1); special masks 1,2
    v2f acc[4][5];                                       // 40 VGPR
    v2f accC[4];                                         // 8 VGPR (e-pair packed)
    #pragma unroll
    for (int p = 0; p < 4; ++p) {
        #pragma unroll
        for (int a2 = 0; a2 < 5; ++a2) acc[p][a2] = b2[a2];
        accC[p] = v2f{0.f, 0.f};
    }

    #pragma unroll
    for (int eg = 0; eg < 8; ++eg) {                     // e-groups of 4; eg=7 -> e=28,29
        const int e0 = eg * 4;
        const bool full = (eg < 7);
        // W rows for this e-group -> SGPR pairs (shared by all 4 pairs)
        v2f wa[5], wb[5], wc[5], wd[5];
        #pragma unroll
        for (int a2 = 0; a2 < 5; ++a2) {
            wa[a2] = v2f{W[(e0    ) * ATT + 2*a2], W[(e0    ) * ATT + 2*a2 + 1]};
            wb[a2] = v2f{W[(e0 + 1) * ATT + 2*a2], W[(e0 + 1) * ATT + 2*a2 + 1]};
        }
        if (full) {
            #pragma unroll
            for (int a2 = 0; a2 < 5; ++a2) {
                wc[a2] = v2f{W[(e0 + 2) * ATT + 2*a2], W[(e0 + 2) * ATT + 2*a2 + 1]};
                wd[a2] = v2f{W[(e0 + 3) * ATT + 2*a2], W[(e0 + 3) * ATT + 2*a2 + 1]};
            }
        }
        const v2f pv01 = v2f{pvec[e0], pvec[e0 + 1]};
        v2f pv23 = v2f{0.f, 0.f};
        if (full) pv23 = v2f{pvec[e0 + 2], pvec[e0 + 3]};

        const float4 xi0 = *reinterpret_cast<const float4*>(&sx[oi0 + e0]);
        const float4 xi1 = *reinterpret_cast<const float4*>(&sx[oi1 + e0]);

        auto do_pair = [&](v2f* ap, v2f& cp, const float4& xi, const float4& xj) {
            const v2f* xiv = reinterpret_cast<const v2f*>(&xi);
            const v2f* xjv = reinterpret_cast<const v2f*>(&xj);
            v2f prL;
            PK_MUL(prL, xiv[0], xjv[0]);
            #pragma unroll
            for (int a2 = 0; a2 < 5; ++a2) PK_FMA_BCLO(ap[a2], prL, wa[a2]);
            #pragma unroll
            for (int a2 = 0; a2 < 5; ++a2) PK_FMA_BCHI(ap[a2], prL, wb[a2]);
            PK_FMA(cp, prL, pv01);
            if (full) {
                v2f prH;
                PK_MUL(prH, xiv[1], xjv[1]);
                #pragma unroll
                for (int a2 = 0; a2 < 5; ++a2) PK_FMA_BCLO(ap[a2], prH, wc[a2]);
                #pragma unroll
                for (int a2 = 0; a2 < 5; ++a2) PK_FMA_BCHI(ap[a2], prH, wd[a2]);
                PK_FMA(cp, prH, pv23);
            }
        };

        {   // column j0: pairs (r0,c0)->slot0, (r1,c0)->slot2
            const float4 xj = *reinterpret_cast<const float4*>(&sx[oj0 + e0]);
            do_pair(acc[0], accC[0], xi0, xj);
            do_pair(acc[2], accC[2], xi1, xj);
        }
        {   // column j1: pairs (r0,c1)->slot1, (r1,c1)->slot3
            const float4 xj = *reinterpret_cast<const float4*>(&sx[oj1 + e0]);
            do_pair(acc[1], accC[1], xi0, xj);
            do_pair(acc[3], accC[3], xi1, xj);
        }
    }

    // ---- epilogue: relu-dot, mask, single-chunk softmax partials ----
    float s4[4], cv4[4];
    #pragma unroll
    for (int p = 0; p < 4; ++p) {
        const v2f z = v2f{0.f, 0.f};
        v2f sv = z;
        #pragma unroll
        for (int a2 = 0; a2 < 5; ++a2) {
            const v2f r = __builtin_elementwise_max(acc[p][a2], z);
            sv = __builtin_elementwise_fma(r, h2[a2], sv);
        }
        s4[p]  = sv.x + sv.y;
        cv4[p] = accC[p].x + accC[p].y;
    }
    if (special) { s4[1] = -INFINITY; s4[2] = -INFINITY; }   // dup / i>j slots

    float m = fmaxf(fmaxf(s4[0], s4[1]), fmaxf(s4[2], s4[3]));
    float se = 0.f, sec = 0.f;
    #pragma unroll
    for (int p = 0; p < 4; ++p) {
        const float E = __expf(s4[p] - m);               // exp(-inf)=0 for masked
        se += E;
        sec = fmaf(E, cv4[p], sec);
    }

    // ---- per-wave butterfly merge of (m,se,sec) ----
    #pragma unroll
    for (int o = 1; o < 64; o <<= 1) {
        const float om  = __shfl_xor(m,   o, 64);
        const float ose = __shfl_xor(se,  o, 64);
        const float osc = __shfl_xor(sec, o, 64);
        const float nm  = fmaxf(m, om);
        const float ea  = __expf(m  - nm);
        const float eb  = __expf(om - nm);
        se  = fmaf(se,  ea, ose * eb);
        sec = fmaf(sec, ea, osc * eb);
        m = nm;
    }
    if (lane == 0) { red[wid][0] = m; red[wid][1] = se; red[wid][2] = sec; }
    __syncthreads();
    if (t == 0) {
        const float m0 = red[0][0], m1 = red[1][0];
        const float M  = fmaxf(m0, m1);
        const float e0 = __expf(m0 - M), e1 = __expf(m1 - M);
        const float SE  = red[0][1] * e0 + red[1][1] * e1;
        const float SEC = red[0][2] * e0 + red[1][2] * e1;
        out[b] = SEC / SE;
    }
}

extern "C" void kernel_launch(void* const* d_in, const int* in_sizes, int n_in,
                              void* d_out, int out_size, void* d_ws, size_t ws_size,
                              hipStream_t stream) {
    const float* x    = (const float*)d_in[0];
    const float* W    = (const float*)d_in[1];
    const float* bias = (const float*)d_in[2];
    const float* h    = (const float*)d_in[3];
    const float* pvec = (const float*)d_in[4];
    float* out = (float*)d_out;

    const int B = in_sizes[0] / (NFEAT * EMB);   // 8192
    attn_net_kernel<<<B, BLK, 0, stream>>>(x, W, bias, h, pvec, out);
}